// Round 21
// baseline (161.046 us; speedup 1.0000x reference)
//
#include <hip/hip_runtime.h>
#include <hip/hip_bf16.h>
#include <stdint.h>

typedef unsigned short u16;
typedef __attribute__((ext_vector_type(8))) short bf16x8;
typedef __attribute__((ext_vector_type(4))) short s16x4;
typedef __attribute__((ext_vector_type(4))) float f32x4;

#define B_DIM 2
#define T_DIM 2048
#define MM_DIM 512
#define S_DIM 3072
#define C_DIM 1024
#define H_DIM 16
#define D_DIM 64
#define QKV_STRIDE 3072
#define SC2F 0.18033688011112042f   // log2(e)/sqrt(64), folded into q
#define GINV 5.545177444479562f     // 1/SC2F, gate compensation

static __device__ __forceinline__ u16 f2b(float f){
  __hip_bfloat16 h = __float2bfloat16(f);
  union { __hip_bfloat16 h; u16 u; } cv; cv.h = h; return cv.u;
}
static __device__ __forceinline__ float b2f(u16 u){
  union { u16 u; __hip_bfloat16 h; } cv; cv.u = u;
  return __bfloat162float(cv.h);
}
// hardware packed f32x2 -> bf16x2 (RNE)
static __device__ __forceinline__ uint32_t cvtpk(float a, float b){
  uint32_t r;
  asm("v_cvt_pk_bf16_f32 %0, %1, %2" : "=v"(r) : "v"(a), "v"(b));
  return r;
}
static __device__ __forceinline__ void gload_lds16(const void* g, void* lds){
  __builtin_amdgcn_global_load_lds((const __attribute__((address_space(1))) uint32_t*)g,
                                   (__attribute__((address_space(3))) uint32_t*)lds, 16, 0, 0);
}

// ---------- merged prep (concat+cast) + LDS-tiled weight transpose ----------
__global__ __launch_bounds__(256) void prep_all_kernel(
    const float* __restrict__ x, const float* __restrict__ fm, const float* __restrict__ rm,
    u16* __restrict__ kvx,
    const float* __restrict__ W0, const float* __restrict__ W1,
    const float* __restrict__ W2, const float* __restrict__ W3,
    u16* __restrict__ WT)
{
  const int PREP_BLOCKS = (B_DIM*S_DIM*C_DIM/8)/256;   // 3072
  if (blockIdx.x < PREP_BLOCKS){
    int idx = blockIdx.x*256 + threadIdx.x;
    long e0 = (long)idx*8;
    int b = (int)(e0 / ((long)S_DIM*C_DIM));
    long r = e0 - (long)b*S_DIM*C_DIM;
    int s  = (int)(r / C_DIM);
    int cc = (int)(r % C_DIM);
    const float* src;
    if (s < T_DIM)              src = x  + ((long)b*T_DIM + s)*C_DIM + cc;
    else if (s < T_DIM+MM_DIM)  src = fm + ((long)b*MM_DIM + (s-T_DIM))*C_DIM + cc;
    else                        src = rm + ((long)b*MM_DIM + (s-T_DIM-MM_DIM))*C_DIM + cc;
    f32x4 a  = *(const f32x4*)src;
    f32x4 b4 = *(const f32x4*)(src+4);
    bf16x8 o;
    o[0]=(short)f2b(a[0]);  o[1]=(short)f2b(a[1]);  o[2]=(short)f2b(a[2]);  o[3]=(short)f2b(a[3]);
    o[4]=(short)f2b(b4[0]); o[5]=(short)f2b(b4[1]); o[6]=(short)f2b(b4[2]); o[7]=(short)f2b(b4[3]);
    *(bf16x8*)(kvx + e0) = o;
  } else {
    __shared__ float ts[64][65];
    const int tb   = blockIdx.x - PREP_BLOCKS;          // 0..1023
    const int widx = tb >> 8;                           // 256 tiles per weight
    const int tile = tb & 255;
    const int n0 = (tile & 15) * 64;
    const int k0 = (tile >> 4) * 64;
    const float* W = (widx==0) ? W0 : (widx==1) ? W1 : (widx==2) ? W2 : W3;
    const int rr = threadIdx.x >> 4;     // 0..15
    const int c4 = threadIdx.x & 15;     // 0..15
    #pragma unroll
    for (int p=0;p<4;p++){
      int row = rr + p*16;
      f32x4 v = *(const f32x4*)(W + (long)(k0+row)*C_DIM + n0 + c4*4);
      ts[row][c4*4+0]=v[0]; ts[row][c4*4+1]=v[1];
      ts[row][c4*4+2]=v[2]; ts[row][c4*4+3]=v[3];
    }
    __syncthreads();
    const int nr = threadIdx.x >> 2;     // 0..63
    const int kc = (threadIdx.x & 3) * 16;
    bf16x8 o0, o1;
    #pragma unroll
    for (int j=0;j<8;j++){
      o0[j] = (short)f2b(ts[kc+j][nr]);
      o1[j] = (short)f2b(ts[kc+8+j][nr]);
    }
    u16* dst = WT + (long)widx*C_DIM*C_DIM + (long)(n0+nr)*C_DIM + k0 + kc;
    *(bf16x8*)dst       = o0;
    *(bf16x8*)(dst + 8) = o1;
  }
}

// ---------- bf16 GEMM (QKV): 128x128 tile, 4 waves, single-buffer (m97/m103
// structure) + rect XCD swizzle + T2 read swizzle + setprio ----------
__global__ __launch_bounds__(256) void gemm_qkv_kernel(
    const u16* __restrict__ A, const u16* __restrict__ Bt,
    u16* __restrict__ Cbf, int N, int K)
{
  __shared__ u16 As[128*64];
  __shared__ u16 Bs[128*64];
  const int tid = threadIdx.x;
  const int w = tid>>6, lane = tid&63, g = lane>>4, c = lane&15;
  const int bid0 = blockIdx.y*gridDim.x + blockIdx.x;
  const int x8 = bid0 & 7, j = bid0 >> 3;          // XCD slot, 0..143
  const int chunk = x8 + 8*(j/48);                 // 0..23
  const int within = j % 48;
  const int bx = (chunk % 3)*8 + (within & 7);     // 0..23
  const int by = (chunk / 3)*6 + (within >> 3);    // 0..47
  if (bx < (C_DIM/128) && (by % 24) >= 16) return; // wasted q x mem tile
  const int wm = (w>>1)*64, wn = (w&1)*64;
  const f32x4 ZERO = {0.f,0.f,0.f,0.f};
  f32x4 acc[4][4];
  #pragma unroll
  for (int m=0;m<4;m++)
    #pragma unroll
    for (int n=0;n<4;n++) acc[m][n] = ZERO;

  const int srow = lane>>3;
  const int scol = 8*((lane&7) ^ srow);   // pre-swizzled global source col
  const int sw   = 8*(c & 7);             // LDS read XOR

  for (int ks=0; ks<K; ks+=64){
    #pragma unroll
    for (int i=0;i<4;i++){
      int ci  = w*4 + i;                  // 16 chunks of 1KB each
      int row = ci*8 + srow;
      gload_lds16(A  + (long)(by*128 + row)*K + ks + scol, (void*)(&As[ci*512]));
      gload_lds16(Bt + (long)(bx*128 + row)*K + ks + scol, (void*)(&Bs[ci*512]));
    }
    __syncthreads();
    __builtin_amdgcn_s_setprio(1);
    #pragma unroll
    for (int kk=0;kk<2;kk++){
      bf16x8 af[4], bfv[4];
      #pragma unroll
      for (int m=0;m<4;m++)
        af[m]  = *(const bf16x8*)(&As[(wm + m*16 + c)*64 + ((kk*32 + g*8) ^ sw)]);
      #pragma unroll
      for (int n=0;n<4;n++)
        bfv[n] = *(const bf16x8*)(&Bs[(wn + n*16 + c)*64 + ((kk*32 + g*8) ^ sw)]);
      #pragma unroll
      for (int m=0;m<4;m++)
        #pragma unroll
        for (int n=0;n<4;n++)
          acc[m][n] = __builtin_amdgcn_mfma_f32_16x16x32_bf16(bfv[n], af[m], acc[m][n], 0,0,0);
    }
    __builtin_amdgcn_s_setprio(0);
    __syncthreads();
  }
  const float osc = (bx < (C_DIM/128)) ? SC2F : 1.0f;   // pre-scale q columns
  #pragma unroll
  for (int m=0;m<4;m++)
    #pragma unroll
    for (int n=0;n<4;n++){
      int row = by*128 + wm + m*16 + c;
      int col = bx*128 + wn + n*16 + 4*g;
      uint2 pv;
      pv.x = cvtpk(acc[m][n][0]*osc, acc[m][n][1]*osc);
      pv.y = cvtpk(acc[m][n][2]*osc, acc[m][n][3]*osc);
      *(uint2*)(Cbf + (long)row*N + col) = pv;
    }
}

// ---------- bf16 GEMM (out-proj): 128x64 tile, 4 waves, DBUF + T2 swizzle ----------
// Per-wave 32x64 (acc[2][4]): 16 MFMA per 12 ds_read_b128 (vs 1.0 ratio of the
// old 64x64 tile); A-panel staged once per 128 rows. Grid 16x32 = 512 (2/CU).
__global__ __launch_bounds__(256) void gemm_out_kernel(
    const u16* __restrict__ A, const u16* __restrict__ Bt,
    float* __restrict__ Cf, int N, int K)
{
  __shared__ u16 As[2][128*64];
  __shared__ u16 Bs[2][64*64];
  const int tid = threadIdx.x;
  const int w = tid>>6, lane = tid&63, g = lane>>4, c = lane&15;
  const int nwg = gridDim.x*gridDim.y;
  const int bid0 = blockIdx.y*gridDim.x + blockIdx.x;
  const int swz = (bid0 & 7)*(nwg >> 3) + (bid0 >> 3);
  const int bx = swz % gridDim.x, by = swz / gridDim.x;
  const int wm = w*32;                 // wave's 32-row slice of the 128-row tile
  const f32x4 ZERO = {0.f,0.f,0.f,0.f};
  f32x4 acc[2][4];
  #pragma unroll
  for (int m=0;m<2;m++)
    #pragma unroll
    for (int n=0;n<4;n++) acc[m][n] = ZERO;

  const int srow = lane>>3;
  const int scol = 8*((lane&7) ^ srow);   // pre-swizzled global source col
  const int sw   = 8*(c & 7);             // LDS read XOR

  // prologue: stage K-step 0
  #pragma unroll
  for (int i=0;i<4;i++){
    int ci  = w*4 + i;                    // A chunks 0..15
    int row = ci*8 + srow;
    gload_lds16(A + (long)(by*128 + row)*K + scol, (void*)(&As[0][ci*512]));
  }
  #pragma unroll
  for (int i=0;i<2;i++){
    int cj  = w*2 + i;                    // B chunks 0..7
    int row = cj*8 + srow;
    gload_lds16(Bt + (long)(bx*64 + row)*K + scol, (void*)(&Bs[0][cj*512]));
  }
  asm volatile("s_waitcnt vmcnt(0)" ::: "memory");
  __syncthreads();

  int cur = 0;
  const int nks = K >> 6;
  for (int t=0; t<nks; ++t){
    if (t+1 < nks){
      int ks = (t+1)*64;
      #pragma unroll
      for (int i=0;i<4;i++){
        int ci  = w*4 + i;
        int row = ci*8 + srow;
        gload_lds16(A + (long)(by*128 + row)*K + ks + scol, (void*)(&As[cur^1][ci*512]));
      }
      #pragma unroll
      for (int i=0;i<2;i++){
        int cj  = w*2 + i;
        int row = cj*8 + srow;
        gload_lds16(Bt + (long)(bx*64 + row)*K + ks + scol, (void*)(&Bs[cur^1][cj*512]));
      }
    }
    __builtin_amdgcn_s_setprio(1);
    #pragma unroll
    for (int kk=0;kk<2;kk++){
      bf16x8 af[2], bfv[4];
      #pragma unroll
      for (int m=0;m<2;m++)
        af[m]  = *(const bf16x8*)(&As[cur][(wm + m*16 + c)*64 + ((kk*32 + g*8) ^ sw)]);
      #pragma unroll
      for (int n=0;n<4;n++)
        bfv[n] = *(const bf16x8*)(&Bs[cur][(n*16 + c)*64 + ((kk*32 + g*8) ^ sw)]);
      #pragma unroll
      for (int m=0;m<2;m++)
        #pragma unroll
        for (int n=0;n<4;n++)
          acc[m][n] = __builtin_amdgcn_mfma_f32_16x16x32_bf16(bfv[n], af[m], acc[m][n], 0,0,0);
    }
    __builtin_amdgcn_s_setprio(0);
    asm volatile("s_waitcnt vmcnt(0)" ::: "memory");
    __syncthreads();
    cur ^= 1;
  }
  #pragma unroll
  for (int m=0;m<2;m++)
    #pragma unroll
    for (int n=0;n<4;n++){
      int row = by*128 + wm + m*16 + c;
      int col = bx*64 + n*16 + 4*g;
      *(f32x4*)(Cf + (long)row*N + col) = acc[m][n];
    }
}

// ---------- gate: vectorized bf16x8 q loads (G13) ----------
__global__ __launch_bounds__(256) void gate_kernel(
    const u16* __restrict__ Qkv, const float* __restrict__ gW, const float* __restrict__ gb,
    float* __restrict__ Gate, float* __restrict__ Part)
{
  __shared__ float qrow[4][1024];
  const int tid = threadIdx.x, w = tid>>6, lane = tid&63;
  const int m = blockIdx.x*4 + w;
  const u16* qp = Qkv + ((long)(m>>11)*S_DIM + (m & (T_DIM-1)))*QKV_STRIDE;
  bf16x8 v0 = *(const bf16x8*)(qp + lane*16);
  bf16x8 v1 = *(const bf16x8*)(qp + lane*16 + 8);
  #pragma unroll
  for (int j=0;j<8;j++){
    qrow[w][lane*16 + j]     = b2f((u16)v0[j]);
    qrow[w][lane*16 + 8 + j] = b2f((u16)v1[j]);
  }
  asm volatile("s_waitcnt lgkmcnt(0)" ::: "memory");
  const int h = lane & 15, sl = lane >> 4;
  float acc = 0.f;
  #pragma unroll 8
  for (int i=0;i<256;i++){
    int cc = sl*256 + i;
    acc += qrow[w][cc] * gW[(long)cc*H_DIM + h];
  }
  acc += __shfl_xor(acc, 16, 64);
  acc += __shfl_xor(acc, 32, 64);
  float gv = 1.0f/(1.0f + __expf(-(acc*GINV + gb[h])));
  float p = gv;
  p += __shfl_xor(p,1,64); p += __shfl_xor(p,2,64);
  p += __shfl_xor(p,4,64); p += __shfl_xor(p,8,64);
  if (lane < 16) Gate[(long)m*H_DIM + lane] = gv;
  if (lane == 0) Part[m] = p;
}

// ---------- loss ----------
__global__ __launch_bounds__(256) void loss_kernel(const float* __restrict__ Part, float* __restrict__ out)
{
  int tid = threadIdx.x;
  float s = 0.f;
  for (int i=tid; i<B_DIM*T_DIM; i+=256) s += Part[i];
  #pragma unroll
  for (int m=1;m<64;m<<=1) s += __shfl_xor(s,m,64);
  __shared__ float red[4];
  if ((tid&63)==0) red[tid>>6] = s;
  __syncthreads();
  if (tid==0)
    out[(long)B_DIM*T_DIM*C_DIM] = 0.01f*(red[0]+red[1]+red[2]+red[3])/(float)(B_DIM*T_DIM*H_DIM);
}

// ---------- fused attention: QBLK=128 (8 waves), KVBLK=64 (R15 structure + T5) ----------
__global__ __launch_bounds__(512) void attn_kernel(
    const u16* __restrict__ Qkv, const float* __restrict__ Gate, u16* __restrict__ Yb)
{
  __shared__ u16 Ks[2][64*64];    // [key][d], phys col = d ^ 8*(key&7)
  __shared__ u16 Vt[2][64*64];    // [d][key], phys col = key ^ 8*(d&7)
  __shared__ u16 Ps[8][16*64];    // per-wave P[q][key], phys col = key ^ 8*(q&7)
  const int tid = threadIdx.x;
  const int w = tid>>6, lane = tid&63, g = lane>>4, c = lane&15;
  const int bid = blockIdx.x;
  const int idx = bid & 31;            // (b,h):  bid%8 = head%8
  const int u2  = (bid>>5)&7;
  const int jh  = bid>>8;
  const int qt2 = jh ? (15 - u2) : u2; // 128-row query tile, 0..15
  const int b = idx >> 4, h = idx & 15;
  const int qrow_w = qt2*128 + w*16;
  const int q_lane = qrow_w + c;
  const f32x4 ZERO = {0.f,0.f,0.f,0.f};

  const u16* Kbase = Qkv + (long)b*S_DIM*QKV_STRIDE + C_DIM + h*D_DIM;
  const u16* Vbase = Kbase + C_DIM;
  const long qrow_g = (long)b*S_DIM + q_lane;

  bf16x8 qf0 = *(const bf16x8*)(Qkv + qrow_g*QKV_STRIDE + h*D_DIM + g*8);
  bf16x8 qf1 = *(const bf16x8*)(Qkv + qrow_g*QKV_STRIDE + h*D_DIM + 32 + g*8);
  const float gq = Gate[((long)b*T_DIM + q_lane)*H_DIM + h];

  f32x4 acc[4];                 // col = q = c, row = d = dn*16 + 4g + r
  #pragma unroll
  for (int dn=0;dn<4;dn++) acc[dn]=ZERO;
  f32x4 lp = ZERO;              // per-lane partial softmax denominator

  const int nLocal = 2*qt2 + 2;            // local 64-key tiles covering q-rows
  const int nTot   = nLocal + (2*MM_DIM)/64;

  const int srow  = lane>>3;
  const int scolK = 8*((lane&7) ^ srow);   // pre-swizzled global source col
  const int sw    = 8*(c & 7);
  const int kp  = 2*(lane & 31);           // V: this thread's key pair
  const int dvt = 8*w + 4*(lane>>5);       // V: this thread's 4-d range

  // prologue: stage tile 0
  {
    gload_lds16(Kbase + (long)(w*8 + srow)*QKV_STRIDE + scolK, (void*)(&Ks[0][w*512]));
    union { s16x4 v; uint32_t d[2]; } u0p, u1p;
    u0p.v = *(const s16x4*)(Vbase + (long)(kp  )*QKV_STRIDE + dvt);
    u1p.v = *(const s16x4*)(Vbase + (long)(kp+1)*QKV_STRIDE + dvt);
    asm volatile("s_waitcnt vmcnt(0)" ::: "memory");
    #pragma unroll
    for (int j2=0;j2<4;j2++){
      int d = dvt + j2;
      uint32_t pv = __builtin_amdgcn_perm(u1p.d[j2>>1], u0p.d[j2>>1],
                                          (j2&1) ? 0x07060302u : 0x05040100u);
      *(uint32_t*)(&Vt[0][d*64 + (kp ^ (8*(d&7)))]) = pv;
    }
  }
  __syncthreads();

  int cur = 0;
  union { s16x4 v; uint32_t d[2]; } u0, u1;
  for (int blk=0; blk<nTot; blk++){
    const int  isMem = (blk >= nLocal);
    const bool last  = (blk+1 == nTot);
    const int  key0  = isMem ? (T_DIM + (blk-nLocal)*64) : blk*64;
    if (!last){
      int nb = blk+1;
      int nk = (nb >= nLocal) ? (T_DIM + (nb-nLocal)*64) : nb*64;
      gload_lds16(Kbase + (long)(nk + w*8 + srow)*QKV_STRIDE + scolK, (void*)(&Ks[cur^1][w*512]));
      u0.v = *(const s16x4*)(Vbase + (long)(nk + kp  )*QKV_STRIDE + dvt);
      u1.v = *(const s16x4*)(Vbase + (long)(nk + kp+1)*QKV_STRIDE + dvt);
    }

    // ---- QK^T swapped: s[n][r2] = score[key=key0+16n+4g+r2][q=q_lane] ----
    f32x4 s[4];
    #pragma unroll
    for (int n=0;n<4;n++) s[n] = ZERO;
    __builtin_amdgcn_s_setprio(1);
    #pragma unroll
    for (int n=0;n<4;n++){
      const u16* kb2 = &Ks[cur][(c + 16*n)*64];
      bf16x8 kf0 = *(const bf16x8*)(kb2 + ((8*g) ^ sw));
      bf16x8 kf1 = *(const bf16x8*)(kb2 + ((32+8*g) ^ sw));
      s[n] = __builtin_amdgcn_mfma_f32_16x16x32_bf16(kf0, qf0, s[n], 0,0,0);
      s[n] = __builtin_amdgcn_mfma_f32_16x16x32_bf16(kf1, qf1, s[n], 0,0,0);
    }
    __builtin_amdgcn_s_setprio(0);
    // causal mask: straddle tiles are blk = 2*qt2 and 2*qt2+1
    if (!isMem && blk >= 2*qt2){
      #pragma unroll
      for (int n=0;n<4;n++)
        #pragma unroll
        for (int r2=0;r2<4;r2++)
          if (key0 + 16*n + 4*g + r2 > q_lane) s[n][r2] = -INFINITY;
    }
    // ---- softmax (no max, no scale): P = exp2(s); gate folded on memory tiles ----
    if (!isMem){
      #pragma unroll
      for (int n=0;n<4;n++)
        #pragma unroll
        for (int r2=0;r2<4;r2++){
          float t = __builtin_amdgcn_exp2f(s[n][r2]);
          lp[r2] += t;
          s[n][r2] = t;
        }
    } else {
      #pragma unroll
      for (int n=0;n<4;n++)
        #pragma unroll
        for (int r2=0;r2<4;r2++){
          float t = __builtin_amdgcn_exp2f(s[n][r2]);
          lp[r2] += t;
          s[n][r2] = gq*t;
        }
    }

    // ---- P -> per-wave LDS (cvt_pk + b64 writes, same-wave DS ordering) ----
    u16* Pb = &Ps[w][0];
    #pragma unroll
    for (int n=0;n<4;n++){
      uint2 pk;
      pk.x = cvtpk(s[n][0], s[n][1]);
      pk.y = cvtpk(s[n][2], s[n][3]);
      *(uint2*)(&Pb[c*64 + ((16*n + 4*g) ^ sw)]) = pk;
    }
    asm volatile("s_waitcnt lgkmcnt(0)" ::: "memory");
    bf16x8 pf0 = *(const bf16x8*)(&Pb[c*64 + ((8*g)    ^ sw)]);
    bf16x8 pf1 = *(const bf16x8*)(&Pb[c*64 + ((32+8*g) ^ sw)]);
    // ---- PV: Yt[d][q] += Vt[d][key] * P[q][key] ----
    __builtin_amdgcn_s_setprio(1);
    #pragma unroll
    for (int dn=0;dn<4;dn++){
      const u16* vb2 = &Vt[cur][(dn*16 + c)*64];
      bf16x8 vf0 = *(const bf16x8*)(vb2 + ((8*g)    ^ sw));
      bf16x8 vf1 = *(const bf16x8*)(vb2 + ((32+8*g) ^ sw));
      acc[dn] = __builtin_amdgcn_mfma_f32_16x16x32_bf16(vf0, pf0, acc[dn], 0,0,0);
      acc[dn] = __builtin_amdgcn_mfma_f32_16x16x32_bf16(vf1, pf1, acc[dn], 0,0,0);
    }
    __builtin_amdgcn_s_setprio(0);
    if (!last){
      asm volatile("s_waitcnt vmcnt(0)" ::: "memory");
      #pragma unroll
      for (int j2=0;j2<4;j2++){
        int d = dvt + j2;
        uint32_t pv = __builtin_amdgcn_perm(u1.d[j2>>1], u0.d[j2>>1],
                                            (j2&1) ? 0x07060302u : 0x05040100u);
        *(uint32_t*)(&Vt[cur^1][d*64 + (kp ^ (8*(d&7)))]) = pv;
      }
      __syncthreads();
      cur ^= 1;
    }
  }
  // ---- finalize: l = reduce(lp); Y = acc/l ----
  float l_r = (lp[0]+lp[1]) + (lp[2]+lp[3]);
  l_r += __shfl_xor(l_r,16,64);
  l_r += __shfl_xor(l_r,32,64);
  float inv = 1.0f / l_r;
  #pragma unroll
  for (int dn=0;dn<4;dn++){
    uint2 o;
    o.x = cvtpk(acc[dn][0]*inv, acc[dn][1]*inv);
    o.y = cvtpk(acc[dn][2]*inv, acc[dn][3]*inv);
    *(uint2*)(Yb + ((long)b*T_DIM + q_lane)*C_DIM + h*D_DIM + dn*16 + 4*g) = o;
  }
}

extern "C" void kernel_launch(void* const* d_in, const int* in_sizes, int n_in,
                              void* d_out, int out_size, void* d_ws, size_t ws_size,
                              hipStream_t stream)
{
  (void)in_sizes; (void)n_in; (void)out_size;
  const float* x  = (const float*)d_in[0];
  const float* fm = (const float*)d_in[1];
  const float* rm = (const float*)d_in[2];
  const float* Wq = (const float*)d_in[3];
  const float* Wk = (const float*)d_in[4];
  const float* Wv = (const float*)d_in[5];
  const float* Wo = (const float*)d_in[6];
  const float* gW = (const float*)d_in[7];
  const float* gb = (const float*)d_in[8];
  float* out = (float*)d_out;

  char* p = (char*)d_ws;
  u16* kvx   = (u16*)p;  p += (long)B_DIM*S_DIM*C_DIM*2;       // reused as yb after QKV GEMM
  u16* qkv   = (u16*)p;  p += (long)B_DIM*S_DIM*QKV_STRIDE*2;
  u16* WqkvT = (u16*)p;  p += (long)3*C_DIM*C_DIM*2;           // WoT follows contiguously
  u16* WoT   = (u16*)p;  p += (long)C_DIM*C_DIM*2;
  float* Gate = (float*)p; p += (long)B_DIM*T_DIM*H_DIM*4;
  float* Part = (float*)p; p += (long)B_DIM*T_DIM*4;
  if ((size_t)(p - (char*)d_ws) > ws_size) return;
  u16* yb = kvx;               // kvx dead after QKV GEMM (8.4MB < 12.6MB)
  (void)WoT;

  // prep cast (3072 blocks) + 4 LDS-tiled weight transposes (1024 blocks)
  prep_all_kernel<<<(B_DIM*S_DIM*C_DIM/8)/256 + 1024, 256, 0, stream>>>(
      x, fm, rm, kvx, Wq, Wk, Wv, Wo, WqkvT);

  // [q|k|v] = kvx @ [Wq|Wk|Wv]   (M=6144, N=3072; grid MUST be 24x48)
  gemm_qkv_kernel<<<dim3(QKV_STRIDE/128, (B_DIM*S_DIM)/128), 256, 0, stream>>>(
      kvx, WqkvT, qkv, QKV_STRIDE, C_DIM);

  gate_kernel<<<(B_DIM*T_DIM)/4, 256, 0, stream>>>(qkv, gW, gb, Gate, Part);
  loss_kernel<<<1, 256, 0, stream>>>(Part, out);

  // attn: 512 blocks x 512 threads (QBLK=128, 8 waves)
  attn_kernel<<<B_DIM*H_DIM*(T_DIM/128), 512, 0, stream>>>(qkv, Gate, yb);

  // out = Y@Wo, 128x64 tiles -> 16x32 = 512 blocks (2/CU)
  gemm_out_kernel<<<dim3(C_DIM/64, (B_DIM*T_DIM)/128), 256, 0, stream>>>(
      yb, WqkvT + (long)3*C_DIM*C_DIM, out, C_DIM, C_DIM);
}

// Round 22
// 160.114 us; speedup vs baseline: 1.0058x; 1.0058x over previous
//
#include <hip/hip_runtime.h>
#include <hip/hip_bf16.h>
#include <stdint.h>

typedef unsigned short u16;
typedef __attribute__((ext_vector_type(8))) short bf16x8;
typedef __attribute__((ext_vector_type(4))) short s16x4;
typedef __attribute__((ext_vector_type(4))) float f32x4;

#define B_DIM 2
#define T_DIM 2048
#define MM_DIM 512
#define S_DIM 3072
#define C_DIM 1024
#define H_DIM 16
#define D_DIM 64
#define QKV_STRIDE 3072
#define SC2F 0.18033688011112042f   // log2(e)/sqrt(64), folded into q
#define GINV 5.545177444479562f     // 1/SC2F, gate compensation

static __device__ __forceinline__ u16 f2b(float f){
  __hip_bfloat16 h = __float2bfloat16(f);
  union { __hip_bfloat16 h; u16 u; } cv; cv.h = h; return cv.u;
}
static __device__ __forceinline__ float b2f(u16 u){
  union { u16 u; __hip_bfloat16 h; } cv; cv.u = u;
  return __bfloat162float(cv.h);
}
// hardware packed f32x2 -> bf16x2 (RNE)
static __device__ __forceinline__ uint32_t cvtpk(float a, float b){
  uint32_t r;
  asm("v_cvt_pk_bf16_f32 %0, %1, %2" : "=v"(r) : "v"(a), "v"(b));
  return r;
}
static __device__ __forceinline__ void gload_lds16(const void* g, void* lds){
  __builtin_amdgcn_global_load_lds((const __attribute__((address_space(1))) uint32_t*)g,
                                   (__attribute__((address_space(3))) uint32_t*)lds, 16, 0, 0);
}

// ---------- merged prep (concat+cast) + LDS-tiled weight transpose ----------
__global__ __launch_bounds__(256) void prep_all_kernel(
    const float* __restrict__ x, const float* __restrict__ fm, const float* __restrict__ rm,
    u16* __restrict__ kvx,
    const float* __restrict__ W0, const float* __restrict__ W1,
    const float* __restrict__ W2, const float* __restrict__ W3,
    u16* __restrict__ WT)
{
  const int PREP_BLOCKS = (B_DIM*S_DIM*C_DIM/8)/256;   // 3072
  if (blockIdx.x < PREP_BLOCKS){
    int idx = blockIdx.x*256 + threadIdx.x;
    long e0 = (long)idx*8;
    int b = (int)(e0 / ((long)S_DIM*C_DIM));
    long r = e0 - (long)b*S_DIM*C_DIM;
    int s  = (int)(r / C_DIM);
    int cc = (int)(r % C_DIM);
    const float* src;
    if (s < T_DIM)              src = x  + ((long)b*T_DIM + s)*C_DIM + cc;
    else if (s < T_DIM+MM_DIM)  src = fm + ((long)b*MM_DIM + (s-T_DIM))*C_DIM + cc;
    else                        src = rm + ((long)b*MM_DIM + (s-T_DIM-MM_DIM))*C_DIM + cc;
    f32x4 a  = *(const f32x4*)src;
    f32x4 b4 = *(const f32x4*)(src+4);
    bf16x8 o;
    o[0]=(short)f2b(a[0]);  o[1]=(short)f2b(a[1]);  o[2]=(short)f2b(a[2]);  o[3]=(short)f2b(a[3]);
    o[4]=(short)f2b(b4[0]); o[5]=(short)f2b(b4[1]); o[6]=(short)f2b(b4[2]); o[7]=(short)f2b(b4[3]);
    *(bf16x8*)(kvx + e0) = o;
  } else {
    __shared__ float ts[64][65];
    const int tb   = blockIdx.x - PREP_BLOCKS;          // 0..1023
    const int widx = tb >> 8;                           // 256 tiles per weight
    const int tile = tb & 255;
    const int n0 = (tile & 15) * 64;
    const int k0 = (tile >> 4) * 64;
    const float* W = (widx==0) ? W0 : (widx==1) ? W1 : (widx==2) ? W2 : W3;
    const int rr = threadIdx.x >> 4;     // 0..15
    const int c4 = threadIdx.x & 15;     // 0..15
    #pragma unroll
    for (int p=0;p<4;p++){
      int row = rr + p*16;
      f32x4 v = *(const f32x4*)(W + (long)(k0+row)*C_DIM + n0 + c4*4);
      ts[row][c4*4+0]=v[0]; ts[row][c4*4+1]=v[1];
      ts[row][c4*4+2]=v[2]; ts[row][c4*4+3]=v[3];
    }
    __syncthreads();
    const int nr = threadIdx.x >> 2;     // 0..63
    const int kc = (threadIdx.x & 3) * 16;
    bf16x8 o0, o1;
    #pragma unroll
    for (int j=0;j<8;j++){
      o0[j] = (short)f2b(ts[kc+j][nr]);
      o1[j] = (short)f2b(ts[kc+8+j][nr]);
    }
    u16* dst = WT + (long)widx*C_DIM*C_DIM + (long)(n0+nr)*C_DIM + k0 + kc;
    *(bf16x8*)dst       = o0;
    *(bf16x8*)(dst + 8) = o1;
  }
}

// ---------- bf16 GEMM (QKV): 128x128 tile, 4 waves, single-buffer (m97/m103
// structure) + rect XCD swizzle + T2 read swizzle + setprio ----------
__global__ __launch_bounds__(256) void gemm_qkv_kernel(
    const u16* __restrict__ A, const u16* __restrict__ Bt,
    u16* __restrict__ Cbf, int N, int K)
{
  __shared__ u16 As[128*64];
  __shared__ u16 Bs[128*64];
  const int tid = threadIdx.x;
  const int w = tid>>6, lane = tid&63, g = lane>>4, c = lane&15;
  const int bid0 = blockIdx.y*gridDim.x + blockIdx.x;
  const int x8 = bid0 & 7, j = bid0 >> 3;          // XCD slot, 0..143
  const int chunk = x8 + 8*(j/48);                 // 0..23
  const int within = j % 48;
  const int bx = (chunk % 3)*8 + (within & 7);     // 0..23
  const int by = (chunk / 3)*6 + (within >> 3);    // 0..47
  if (bx < (C_DIM/128) && (by % 24) >= 16) return; // wasted q x mem tile
  const int wm = (w>>1)*64, wn = (w&1)*64;
  const f32x4 ZERO = {0.f,0.f,0.f,0.f};
  f32x4 acc[4][4];
  #pragma unroll
  for (int m=0;m<4;m++)
    #pragma unroll
    for (int n=0;n<4;n++) acc[m][n] = ZERO;

  const int srow = lane>>3;
  const int scol = 8*((lane&7) ^ srow);   // pre-swizzled global source col
  const int sw   = 8*(c & 7);             // LDS read XOR

  for (int ks=0; ks<K; ks+=64){
    #pragma unroll
    for (int i=0;i<4;i++){
      int ci  = w*4 + i;                  // 16 chunks of 1KB each
      int row = ci*8 + srow;
      gload_lds16(A  + (long)(by*128 + row)*K + ks + scol, (void*)(&As[ci*512]));
      gload_lds16(Bt + (long)(bx*128 + row)*K + ks + scol, (void*)(&Bs[ci*512]));
    }
    __syncthreads();
    __builtin_amdgcn_s_setprio(1);
    #pragma unroll
    for (int kk=0;kk<2;kk++){
      bf16x8 af[4], bfv[4];
      #pragma unroll
      for (int m=0;m<4;m++)
        af[m]  = *(const bf16x8*)(&As[(wm + m*16 + c)*64 + ((kk*32 + g*8) ^ sw)]);
      #pragma unroll
      for (int n=0;n<4;n++)
        bfv[n] = *(const bf16x8*)(&Bs[(wn + n*16 + c)*64 + ((kk*32 + g*8) ^ sw)]);
      #pragma unroll
      for (int m=0;m<4;m++)
        #pragma unroll
        for (int n=0;n<4;n++)
          acc[m][n] = __builtin_amdgcn_mfma_f32_16x16x32_bf16(bfv[n], af[m], acc[m][n], 0,0,0);
    }
    __builtin_amdgcn_s_setprio(0);
    __syncthreads();
  }
  const float osc = (bx < (C_DIM/128)) ? SC2F : 1.0f;   // pre-scale q columns
  #pragma unroll
  for (int m=0;m<4;m++)
    #pragma unroll
    for (int n=0;n<4;n++){
      int row = by*128 + wm + m*16 + c;
      int col = bx*128 + wn + n*16 + 4*g;
      uint2 pv;
      pv.x = cvtpk(acc[m][n][0]*osc, acc[m][n][1]*osc);
      pv.y = cvtpk(acc[m][n][2]*osc, acc[m][n][3]*osc);
      *(uint2*)(Cbf + (long)row*N + col) = pv;
    }
}

// ---------- bf16 GEMM, 64x64 tile (out-proj): DBUF + T2 swizzle (R20 best) ----------
__global__ __launch_bounds__(256) void gemm_out_kernel(
    const u16* __restrict__ A, const u16* __restrict__ Bt,
    float* __restrict__ Cf, int N, int K)
{
  __shared__ u16 As[2][64*64];
  __shared__ u16 Bs[2][64*64];
  const int tid = threadIdx.x;
  const int w = tid>>6, lane = tid&63, g = lane>>4, c = lane&15;
  const int nwg = gridDim.x*gridDim.y;
  const int bid0 = blockIdx.y*gridDim.x + blockIdx.x;
  const int swz = (bid0 & 7)*(nwg >> 3) + (bid0 >> 3);
  const int bx = swz % gridDim.x, by = swz / gridDim.x;
  const int wm = (w>>1)*32, wn = (w&1)*32;
  const f32x4 ZERO = {0.f,0.f,0.f,0.f};
  f32x4 acc[2][2];
  #pragma unroll
  for (int m=0;m<2;m++)
    #pragma unroll
    for (int n=0;n<2;n++) acc[m][n] = ZERO;

  const int srow = lane>>3;
  const int scol = 8*((lane&7) ^ srow);   // pre-swizzled global source col
  const int sw   = 8*(c & 7);             // LDS read XOR

  // prologue: stage K-step 0
  #pragma unroll
  for (int i=0;i<2;i++){
    int ci  = 2*w + i;            // chunks 0..7
    int row = ci*8 + srow;
    gload_lds16(A  + (long)(by*64 + row)*K + scol, (void*)(&As[0][ci*512]));
    gload_lds16(Bt + (long)(bx*64 + row)*K + scol, (void*)(&Bs[0][ci*512]));
  }
  asm volatile("s_waitcnt vmcnt(0)" ::: "memory");
  __syncthreads();

  int cur = 0;
  const int nks = K >> 6;
  for (int t=0; t<nks; ++t){
    if (t+1 < nks){
      int ks = (t+1)*64;
      #pragma unroll
      for (int i=0;i<2;i++){
        int ci  = 2*w + i;
        int row = ci*8 + srow;
        gload_lds16(A  + (long)(by*64 + row)*K + ks + scol, (void*)(&As[cur^1][ci*512]));
        gload_lds16(Bt + (long)(bx*64 + row)*K + ks + scol, (void*)(&Bs[cur^1][ci*512]));
      }
    }
    __builtin_amdgcn_s_setprio(1);
    #pragma unroll
    for (int kk=0;kk<2;kk++){
      bf16x8 af[2], bfv[2];
      #pragma unroll
      for (int m=0;m<2;m++)
        af[m]  = *(const bf16x8*)(&As[cur][(wm + m*16 + c)*64 + ((kk*32 + g*8) ^ sw)]);
      #pragma unroll
      for (int n=0;n<2;n++)
        bfv[n] = *(const bf16x8*)(&Bs[cur][(wn + n*16 + c)*64 + ((kk*32 + g*8) ^ sw)]);
      #pragma unroll
      for (int m=0;m<2;m++)
        #pragma unroll
        for (int n=0;n<2;n++)
          acc[m][n] = __builtin_amdgcn_mfma_f32_16x16x32_bf16(bfv[n], af[m], acc[m][n], 0,0,0);
    }
    __builtin_amdgcn_s_setprio(0);
    asm volatile("s_waitcnt vmcnt(0)" ::: "memory");
    __syncthreads();
    cur ^= 1;
  }
  #pragma unroll
  for (int m=0;m<2;m++)
    #pragma unroll
    for (int n=0;n<2;n++){
      int row = by*64 + wm + m*16 + c;
      int col = bx*64 + wn + n*16 + 4*g;
      *(f32x4*)(Cf + (long)row*N + col) = acc[m][n];
    }
}

// ---------- gate: vectorized bf16x8 q loads (G13) ----------
__global__ __launch_bounds__(256) void gate_kernel(
    const u16* __restrict__ Qkv, const float* __restrict__ gW, const float* __restrict__ gb,
    float* __restrict__ Gate, float* __restrict__ Part)
{
  __shared__ float qrow[4][1024];
  const int tid = threadIdx.x, w = tid>>6, lane = tid&63;
  const int m = blockIdx.x*4 + w;
  const u16* qp = Qkv + ((long)(m>>11)*S_DIM + (m & (T_DIM-1)))*QKV_STRIDE;
  bf16x8 v0 = *(const bf16x8*)(qp + lane*16);
  bf16x8 v1 = *(const bf16x8*)(qp + lane*16 + 8);
  #pragma unroll
  for (int j=0;j<8;j++){
    qrow[w][lane*16 + j]     = b2f((u16)v0[j]);
    qrow[w][lane*16 + 8 + j] = b2f((u16)v1[j]);
  }
  asm volatile("s_waitcnt lgkmcnt(0)" ::: "memory");
  const int h = lane & 15, sl = lane >> 4;
  float acc = 0.f;
  #pragma unroll 8
  for (int i=0;i<256;i++){
    int cc = sl*256 + i;
    acc += qrow[w][cc] * gW[(long)cc*H_DIM + h];
  }
  acc += __shfl_xor(acc, 16, 64);
  acc += __shfl_xor(acc, 32, 64);
  float gv = 1.0f/(1.0f + __expf(-(acc*GINV + gb[h])));
  float p = gv;
  p += __shfl_xor(p,1,64); p += __shfl_xor(p,2,64);
  p += __shfl_xor(p,4,64); p += __shfl_xor(p,8,64);
  if (lane < 16) Gate[(long)m*H_DIM + lane] = gv;
  if (lane == 0) Part[m] = p;
}

// ---------- loss ----------
__global__ __launch_bounds__(256) void loss_kernel(const float* __restrict__ Part, float* __restrict__ out)
{
  int tid = threadIdx.x;
  float s = 0.f;
  for (int i=tid; i<B_DIM*T_DIM; i+=256) s += Part[i];
  #pragma unroll
  for (int m=1;m<64;m<<=1) s += __shfl_xor(s,m,64);
  __shared__ float red[4];
  if ((tid&63)==0) red[tid>>6] = s;
  __syncthreads();
  if (tid==0)
    out[(long)B_DIM*T_DIM*C_DIM] = 0.01f*(red[0]+red[1]+red[2]+red[3])/(float)(B_DIM*T_DIM*H_DIM);
}

// ---------- fused attention: QBLK=128 (8 waves), KVBLK=64 (R15 structure + T5) ----------
__global__ __launch_bounds__(512) void attn_kernel(
    const u16* __restrict__ Qkv, const float* __restrict__ Gate, u16* __restrict__ Yb)
{
  __shared__ u16 Ks[2][64*64];    // [key][d], phys col = d ^ 8*(key&7)
  __shared__ u16 Vt[2][64*64];    // [d][key], phys col = key ^ 8*(d&7)
  __shared__ u16 Ps[8][16*64];    // per-wave P[q][key], phys col = key ^ 8*(q&7)
  const int tid = threadIdx.x;
  const int w = tid>>6, lane = tid&63, g = lane>>4, c = lane&15;
  const int bid = blockIdx.x;
  const int idx = bid & 31;            // (b,h):  bid%8 = head%8
  const int u2  = (bid>>5)&7;
  const int jh  = bid>>8;
  const int qt2 = jh ? (15 - u2) : u2; // 128-row query tile, 0..15
  const int b = idx >> 4, h = idx & 15;
  const int qrow_w = qt2*128 + w*16;
  const int q_lane = qrow_w + c;
  const f32x4 ZERO = {0.f,0.f,0.f,0.f};

  const u16* Kbase = Qkv + (long)b*S_DIM*QKV_STRIDE + C_DIM + h*D_DIM;
  const u16* Vbase = Kbase + C_DIM;
  const long qrow_g = (long)b*S_DIM + q_lane;

  bf16x8 qf0 = *(const bf16x8*)(Qkv + qrow_g*QKV_STRIDE + h*D_DIM + g*8);
  bf16x8 qf1 = *(const bf16x8*)(Qkv + qrow_g*QKV_STRIDE + h*D_DIM + 32 + g*8);
  const float gq = Gate[((long)b*T_DIM + q_lane)*H_DIM + h];

  f32x4 acc[4];                 // col = q = c, row = d = dn*16 + 4g + r
  #pragma unroll
  for (int dn=0;dn<4;dn++) acc[dn]=ZERO;
  f32x4 lp = ZERO;              // per-lane partial softmax denominator

  const int nLocal = 2*qt2 + 2;            // local 64-key tiles covering q-rows
  const int nTot   = nLocal + (2*MM_DIM)/64;

  const int srow  = lane>>3;
  const int scolK = 8*((lane&7) ^ srow);   // pre-swizzled global source col
  const int sw    = 8*(c & 7);
  const int kp  = 2*(lane & 31);           // V: this thread's key pair
  const int dvt = 8*w + 4*(lane>>5);       // V: this thread's 4-d range

  // prologue: stage tile 0
  {
    gload_lds16(Kbase + (long)(w*8 + srow)*QKV_STRIDE + scolK, (void*)(&Ks[0][w*512]));
    union { s16x4 v; uint32_t d[2]; } u0p, u1p;
    u0p.v = *(const s16x4*)(Vbase + (long)(kp  )*QKV_STRIDE + dvt);
    u1p.v = *(const s16x4*)(Vbase + (long)(kp+1)*QKV_STRIDE + dvt);
    asm volatile("s_waitcnt vmcnt(0)" ::: "memory");
    #pragma unroll
    for (int j2=0;j2<4;j2++){
      int d = dvt + j2;
      uint32_t pv = __builtin_amdgcn_perm(u1p.d[j2>>1], u0p.d[j2>>1],
                                          (j2&1) ? 0x07060302u : 0x05040100u);
      *(uint32_t*)(&Vt[0][d*64 + (kp ^ (8*(d&7)))]) = pv;
    }
  }
  __syncthreads();

  int cur = 0;
  union { s16x4 v; uint32_t d[2]; } u0, u1;
  for (int blk=0; blk<nTot; blk++){
    const int  isMem = (blk >= nLocal);
    const bool last  = (blk+1 == nTot);
    const int  key0  = isMem ? (T_DIM + (blk-nLocal)*64) : blk*64;
    if (!last){
      int nb = blk+1;
      int nk = (nb >= nLocal) ? (T_DIM + (nb-nLocal)*64) : nb*64;
      gload_lds16(Kbase + (long)(nk + w*8 + srow)*QKV_STRIDE + scolK, (void*)(&Ks[cur^1][w*512]));
      u0.v = *(const s16x4*)(Vbase + (long)(nk + kp  )*QKV_STRIDE + dvt);
      u1.v = *(const s16x4*)(Vbase + (long)(nk + kp+1)*QKV_STRIDE + dvt);
    }

    // ---- QK^T swapped: s[n][r2] = score[key=key0+16n+4g+r2][q=q_lane] ----
    f32x4 s[4];
    #pragma unroll
    for (int n=0;n<4;n++) s[n] = ZERO;
    __builtin_amdgcn_s_setprio(1);
    #pragma unroll
    for (int n=0;n<4;n++){
      const u16* kb2 = &Ks[cur][(c + 16*n)*64];
      bf16x8 kf0 = *(const bf16x8*)(kb2 + ((8*g) ^ sw));
      bf16x8 kf1 = *(const bf16x8*)(kb2 + ((32+8*g) ^ sw));
      s[n] = __builtin_amdgcn_mfma_f32_16x16x32_bf16(kf0, qf0, s[n], 0,0,0);
      s[n] = __builtin_amdgcn_mfma_f32_16x16x32_bf16(kf1, qf1, s[n], 0,0,0);
    }
    __builtin_amdgcn_s_setprio(0);
    // causal mask: straddle tiles are blk = 2*qt2 and 2*qt2+1
    if (!isMem && blk >= 2*qt2){
      #pragma unroll
      for (int n=0;n<4;n++)
        #pragma unroll
        for (int r2=0;r2<4;r2++)
          if (key0 + 16*n + 4*g + r2 > q_lane) s[n][r2] = -INFINITY;
    }
    // ---- softmax (no max, no scale): P = exp2(s); gate folded on memory tiles ----
    if (!isMem){
      #pragma unroll
      for (int n=0;n<4;n++)
        #pragma unroll
        for (int r2=0;r2<4;r2++){
          float t = __builtin_amdgcn_exp2f(s[n][r2]);
          lp[r2] += t;
          s[n][r2] = t;
        }
    } else {
      #pragma unroll
      for (int n=0;n<4;n++)
        #pragma unroll
        for (int r2=0;r2<4;r2++){
          float t = __builtin_amdgcn_exp2f(s[n][r2]);
          lp[r2] += t;
          s[n][r2] = gq*t;
        }
    }

    // ---- P -> per-wave LDS (cvt_pk + b64 writes, same-wave DS ordering) ----
    u16* Pb = &Ps[w][0];
    #pragma unroll
    for (int n=0;n<4;n++){
      uint2 pk;
      pk.x = cvtpk(s[n][0], s[n][1]);
      pk.y = cvtpk(s[n][2], s[n][3]);
      *(uint2*)(&Pb[c*64 + ((16*n + 4*g) ^ sw)]) = pk;
    }
    asm volatile("s_waitcnt lgkmcnt(0)" ::: "memory");
    bf16x8 pf0 = *(const bf16x8*)(&Pb[c*64 + ((8*g)    ^ sw)]);
    bf16x8 pf1 = *(const bf16x8*)(&Pb[c*64 + ((32+8*g) ^ sw)]);
    // ---- PV: Yt[d][q] += Vt[d][key] * P[q][key] ----
    __builtin_amdgcn_s_setprio(1);
    #pragma unroll
    for (int dn=0;dn<4;dn++){
      const u16* vb2 = &Vt[cur][(dn*16 + c)*64];
      bf16x8 vf0 = *(const bf16x8*)(vb2 + ((8*g)    ^ sw));
      bf16x8 vf1 = *(const bf16x8*)(vb2 + ((32+8*g) ^ sw));
      acc[dn] = __builtin_amdgcn_mfma_f32_16x16x32_bf16(vf0, pf0, acc[dn], 0,0,0);
      acc[dn] = __builtin_amdgcn_mfma_f32_16x16x32_bf16(vf1, pf1, acc[dn], 0,0,0);
    }
    __builtin_amdgcn_s_setprio(0);
    if (!last){
      asm volatile("s_waitcnt vmcnt(0)" ::: "memory");
      #pragma unroll
      for (int j2=0;j2<4;j2++){
        int d = dvt + j2;
        uint32_t pv = __builtin_amdgcn_perm(u1.d[j2>>1], u0.d[j2>>1],
                                            (j2&1) ? 0x07060302u : 0x05040100u);
        *(uint32_t*)(&Vt[cur^1][d*64 + (kp ^ (8*(d&7)))]) = pv;
      }
      __syncthreads();
      cur ^= 1;
    }
  }
  // ---- finalize: l = reduce(lp); Y = acc/l ----
  float l_r = (lp[0]+lp[1]) + (lp[2]+lp[3]);
  l_r += __shfl_xor(l_r,16,64);
  l_r += __shfl_xor(l_r,32,64);
  float inv = 1.0f / l_r;
  #pragma unroll
  for (int dn=0;dn<4;dn++){
    uint2 o;
    o.x = cvtpk(acc[dn][0]*inv, acc[dn][1]*inv);
    o.y = cvtpk(acc[dn][2]*inv, acc[dn][3]*inv);
    *(uint2*)(Yb + ((long)b*T_DIM + q_lane)*C_DIM + h*D_DIM + dn*16 + 4*g) = o;
  }
}

extern "C" void kernel_launch(void* const* d_in, const int* in_sizes, int n_in,
                              void* d_out, int out_size, void* d_ws, size_t ws_size,
                              hipStream_t stream)
{
  (void)in_sizes; (void)n_in; (void)out_size;
  const float* x  = (const float*)d_in[0];
  const float* fm = (const float*)d_in[1];
  const float* rm = (const float*)d_in[2];
  const float* Wq = (const float*)d_in[3];
  const float* Wk = (const float*)d_in[4];
  const float* Wv = (const float*)d_in[5];
  const float* Wo = (const float*)d_in[6];
  const float* gW = (const float*)d_in[7];
  const float* gb = (const float*)d_in[8];
  float* out = (float*)d_out;

  char* p = (char*)d_ws;
  u16* kvx   = (u16*)p;  p += (long)B_DIM*S_DIM*C_DIM*2;       // reused as yb after QKV GEMM
  u16* qkv   = (u16*)p;  p += (long)B_DIM*S_DIM*QKV_STRIDE*2;
  u16* WqkvT = (u16*)p;  p += (long)3*C_DIM*C_DIM*2;           // WoT follows contiguously
  u16* WoT   = (u16*)p;  p += (long)C_DIM*C_DIM*2;
  float* Gate = (float*)p; p += (long)B_DIM*T_DIM*H_DIM*4;
  float* Part = (float*)p; p += (long)B_DIM*T_DIM*4;
  if ((size_t)(p - (char*)d_ws) > ws_size) return;
  u16* yb = kvx;               // kvx dead after QKV GEMM (8.4MB < 12.6MB)
  (void)WoT;

  // prep cast (3072 blocks) + 4 LDS-tiled weight transposes (1024 blocks)
  prep_all_kernel<<<(B_DIM*S_DIM*C_DIM/8)/256 + 1024, 256, 0, stream>>>(
      x, fm, rm, kvx, Wq, Wk, Wv, Wo, WqkvT);

  // [q|k|v] = kvx @ [Wq|Wk|Wv]   (M=6144, N=3072; grid MUST be 24x48)
  gemm_qkv_kernel<<<dim3(QKV_STRIDE/128, (B_DIM*S_DIM)/128), 256, 0, stream>>>(
      kvx, WqkvT, qkv, QKV_STRIDE, C_DIM);

  gate_kernel<<<(B_DIM*T_DIM)/4, 256, 0, stream>>>(qkv, gW, gb, Gate, Part);
  loss_kernel<<<1, 256, 0, stream>>>(Part, out);

  // attn: 512 blocks x 512 threads (QBLK=128, 8 waves)
  attn_kernel<<<B_DIM*H_DIM*(T_DIM/128), 512, 0, stream>>>(qkv, Gate, yb);

  // out = Y@Wo, 64x64 tiles -> 1024 blocks = 4/CU
  gemm_out_kernel<<<dim3(C_DIM/64, (B_DIM*T_DIM)/64), 256, 0, stream>>>(
      yb, WqkvT + (long)3*C_DIM*C_DIM, out, C_DIM, C_DIM);
}